// Round 10
// baseline (45.379 us; speedup 1.0000x reference)
//
#include <hip/hip_runtime.h>

#define NBINS 128
#define NFREQ 64
#define HDIM 128
#define NQ 16384
#define EPSF 1e-8f

typedef _Float16 h2 __attribute__((ext_vector_type(2)));
#define B2(x) __builtin_bit_cast(h2, (x))
#define U32(x) __builtin_bit_cast(unsigned, (x))

__device__ __forceinline__ h2 cvt_pk(float a, float b) {
  return __builtin_bit_cast(h2, __builtin_amdgcn_cvt_pkrtz(a, b));
}

// d_ws: per (bin, fh) record of 64 u32 words, contiguous 256 B:
//   ep[32]: (pr,pi) h2 per freq f = fh*32+j
//   wp[16]: (-softplus(w)) h2 pairs     mp[16]: (mw) h2 pairs
// 128 bins * 2 fh * 256 B = 64 KiB. Read via wave-uniform s_load in scorer.
#define WS_NEEDED (64 * 1024)

// ---------- tiny probe pack (1 block) ----------
__global__ __launch_bounds__(256) void pack10(
    const float* __restrict__ probes,
    const float* __restrict__ wraw,
    const float* __restrict__ mw,
    unsigned* __restrict__ ws) {
  const int id = threadIdx.x;  // (b, fh)
  const int b = id >> 1, fh = id & 1, f0 = fh * 32;
  unsigned* rec = ws + (size_t)id * 64;
  #pragma unroll 1
  for (int c = 0; c < 4; ++c) {  // 4 chunks of 8 freqs, low VGPR
    const int f = f0 + c * 8;
    float pr[8], pi[8], w[8], m[8];
    *reinterpret_cast<float4*>(&pr[0]) = *reinterpret_cast<const float4*>(probes + b * HDIM + f);
    *reinterpret_cast<float4*>(&pr[4]) = *reinterpret_cast<const float4*>(probes + b * HDIM + f + 4);
    *reinterpret_cast<float4*>(&pi[0]) = *reinterpret_cast<const float4*>(probes + b * HDIM + NFREQ + f);
    *reinterpret_cast<float4*>(&pi[4]) = *reinterpret_cast<const float4*>(probes + b * HDIM + NFREQ + f + 4);
    *reinterpret_cast<float4*>(&w[0])  = *reinterpret_cast<const float4*>(wraw + b * NFREQ + f);
    *reinterpret_cast<float4*>(&w[4])  = *reinterpret_cast<const float4*>(wraw + b * NFREQ + f + 4);
    *reinterpret_cast<float4*>(&m[0])  = *reinterpret_cast<const float4*>(mw + b * NFREQ + f);
    *reinterpret_cast<float4*>(&m[4])  = *reinterpret_cast<const float4*>(mw + b * NFREQ + f + 4);
    #pragma unroll
    for (int k = 0; k < 8; ++k) {
      h2 v = {(_Float16)pr[k], (_Float16)pi[k]};
      rec[c * 8 + k] = U32(v);
    }
    #pragma unroll
    for (int k2 = 0; k2 < 4; ++k2) {
      float w0 = w[2 * k2], w1 = w[2 * k2 + 1];
      float n0 = -(fmaxf(w0, 0.0f) + log1pf(expf(-fabsf(w0))));
      float n1 = -(fmaxf(w1, 0.0f) + log1pf(expf(-fabsf(w1))));
      h2 vw = {(_Float16)n0, (_Float16)n1};
      h2 vm = {(_Float16)m[2 * k2], (_Float16)m[2 * k2 + 1]};
      rec[32 + c * 4 + k2] = U32(vw);
      rec[48 + c * 4 + k2] = U32(vm);
    }
  }
}

// ---------- scorer: lane = query; probes scalar (SMEM); Q per-lane VGPR ----------
// Block 512 thr = 8 waves: wave w -> bqi = w&3 (16 bins), fh = w>>2 (32 freqs).
// blockIdx: qc = bid>>1 (64 queries), bh = bid&1 (bin half of 64).
// Inner loop touches NO LDS and NO vector memory — pure VALU/trans + SGPR operands.
__global__ __launch_bounds__(512) void scorer10(
    const float* __restrict__ Q,
    const unsigned* __restrict__ ws,
    const float* __restrict__ bias,
    float* __restrict__ out) {
  __shared__ unsigned qpk[96 * 64];   // 24 KB: word-plane j (0..95) x q (0..63)
  __shared__ float part[4][64][17];   // 17.4 KB, pad 17 -> conflict-free
  const int t = threadIdx.x;
  const int qblk = (blockIdx.x >> 1) * 64;
  const int bh = blockIdx.x & 1;

  // ---- Phase 1: cooperative normalize of the block's 64 queries ----
  {
    const int q8 = t >> 3;   // query 0..63
    const int seg = t & 7;   // 8 freqs: f0 = seg*8
    const float* qp = Q + (size_t)(qblk + q8) * HDIM + seg * 8;
    const float4 r0 = *reinterpret_cast<const float4*>(qp);
    const float4 r1 = *reinterpret_cast<const float4*>(qp + 4);
    const float4 i0 = *reinterpret_cast<const float4*>(qp + NFREQ);
    const float4 i1 = *reinterpret_cast<const float4*>(qp + NFREQ + 4);
    float s = r0.x*r0.x + r0.y*r0.y + r0.z*r0.z + r0.w*r0.w
            + r1.x*r1.x + r1.y*r1.y + r1.z*r1.z + r1.w*r1.w
            + i0.x*i0.x + i0.y*i0.y + i0.z*i0.z + i0.w*i0.w
            + i1.x*i1.x + i1.y*i1.y + i1.z*i1.z + i1.w*i1.w;
    s += __shfl_xor(s, 1, 8);
    s += __shfl_xor(s, 2, 8);
    s += __shfl_xor(s, 4, 8);
    const float inv = 1.0f / (__builtin_amdgcn_sqrtf(s) + EPSF);
    const float re[8] = {r0.x, r0.y, r0.z, r0.w, r1.x, r1.y, r1.z, r1.w};
    const float im[8] = {i0.x, i0.y, i0.z, i0.w, i1.x, i1.y, i1.z, i1.w};
    float qr[8], qi[8];
    #pragma unroll
    for (int k = 0; k < 8; ++k) {
      qr[k] = re[k] * inv;
      qi[k] = im[k] * inv;
      h2 v = {(_Float16)(-qr[k]), (_Float16)(-qi[k])};
      qpk[(seg * 8 + k) * 64 + q8] = U32(v);    // ep planes 0..63
    }
    #pragma unroll
    for (int k2 = 0; k2 < 4; ++k2) {
      const float qm0 = __builtin_amdgcn_sqrtf(
          fmaf(qr[2*k2], qr[2*k2], fmaf(qi[2*k2], qi[2*k2], EPSF)));
      const float qm1 = __builtin_amdgcn_sqrtf(
          fmaf(qr[2*k2+1], qr[2*k2+1], fmaf(qi[2*k2+1], qi[2*k2+1], EPSF)));
      h2 v = {(_Float16)qm0, (_Float16)qm1};
      qpk[(64 + seg * 4 + k2) * 64 + q8] = U32(v);  // qm planes 64..95
    }
  }
  __syncthreads();

  // ---- Phase 2: pull this wave's q-data into VGPRs (once; conflict-free b32) ----
  const int lane = t & 63;
  const int w = __builtin_amdgcn_readfirstlane(t >> 6);
  const int bqi = w & 3;
  const int fh = w >> 2;
  const int b0 = bh * 64 + bqi * 16;

  unsigned eq[32], qmw[16];
  #pragma unroll
  for (int j = 0; j < 32; ++j) eq[j] = qpk[(fh * 32 + j) * 64 + lane];
  #pragma unroll
  for (int k = 0; k < 16; ++k) qmw[k] = qpk[(64 + fh * 16 + k) * 64 + lane];

  // ---- Phase 3: 16 bins x 32 freqs; probe record via wave-uniform s_load ----
  float acc[16];
  #pragma unroll 1
  for (int bi = 0; bi < 16; ++bi) {
    const int rbase = __builtin_amdgcn_readfirstlane(((b0 + bi) * 2 + fh) * 64);
    const unsigned* rec = ws + rbase;
    float da = 0.0f, ma = 0.0f;
    #pragma unroll
    for (int p = 0; p < 16; ++p) {
      h2 e0 = B2(rec[2 * p])     + B2(eq[2 * p]);      // v_pk_add_f16 (1 SGPR src)
      h2 e1 = B2(rec[2 * p + 1]) + B2(eq[2 * p + 1]);
      float d0 = __builtin_amdgcn_fdot2(e0, e0, EPSF, false);
      float d1 = __builtin_amdgcn_fdot2(e1, e1, EPSF, false);
      h2 dp = cvt_pk(__builtin_amdgcn_sqrtf(d0), __builtin_amdgcn_sqrtf(d1));
      da = __builtin_amdgcn_fdot2(dp, B2(rec[32 + p]), da, false);
      ma = __builtin_amdgcn_fdot2(B2(qmw[p]), B2(rec[48 + p]), ma, false);
    }
    acc[bi] = da + ma;
  }

  // ---- Phase 4: fh-combine + store (full 64B line per lane) ----
  if (fh == 1) {
    #pragma unroll
    for (int bi = 0; bi < 16; ++bi) part[bqi][lane][bi] = acc[bi];
  }
  __syncthreads();
  if (fh == 0) {
    float v[16];
    #pragma unroll
    for (int bi = 0; bi < 16; ++bi)
      v[bi] = acc[bi] + part[bqi][lane][bi] + bias[b0 + bi];
    float* op = out + (size_t)(qblk + lane) * NBINS + b0;
    #pragma unroll
    for (int g = 0; g < 4; ++g)
      *reinterpret_cast<float4*>(op + g * 4) =
          make_float4(v[g * 4], v[g * 4 + 1], v[g * 4 + 2], v[g * 4 + 3]);
  }
}

extern "C" void kernel_launch(void* const* d_in, const int* in_sizes, int n_in,
                              void* d_out, int out_size, void* d_ws, size_t ws_size,
                              hipStream_t stream) {
  const float* Q      = (const float*)d_in[0];
  const float* probes = (const float*)d_in[1];
  const float* wraw   = (const float*)d_in[2];
  const float* mw     = (const float*)d_in[3];
  const float* bias   = (const float*)d_in[4];
  float* out = (float*)d_out;
  unsigned* ws = (unsigned*)d_ws;  // 64 KiB needed; harness provides far more

  pack10<<<1, 256, 0, stream>>>(probes, wraw, mw, ws);
  scorer10<<<512, 512, 0, stream>>>(Q, ws, bias, out);
}

// Round 11
// 37.321 us; speedup vs baseline: 1.2159x; 1.2159x over previous
//
#include <hip/hip_runtime.h>

#define NBINS 128
#define NFREQ 64
#define HDIM 128
#define NQ 16384
#define EPSF 1e-8f

typedef _Float16 h2 __attribute__((ext_vector_type(2)));
#define B2(x) __builtin_bit_cast(h2, (x))
#define U32(x) __builtin_bit_cast(unsigned, (x))

__device__ __forceinline__ h2 cvt_pk(float a, float b) {
  return __builtin_bit_cast(h2, __builtin_amdgcn_cvt_pkrtz(a, b));
}

// d_ws layout (f16 probe pack, 64 KiB; identical to round 9):
//   EP[c][b][fj] : (pr,pi) h2 word; c=0..7 (8-freq chunk), b=0..127, fj=0..7
//                  word idx (c*128+b)*8+fj                       -> 32 KiB
//   WP[c][b][fp] : (-softplus(w)) h2 pairs                       -> @ +8192 words
//   MP[c][b][fp] : (mw) h2 pairs                                 -> @ +12288 words
#define WS_NEEDED (64 * 1024)

// ---------- probe-pack kernel (unchanged from round 9) ----------
__global__ __launch_bounds__(256) void pack8(
    const float* __restrict__ probes,
    const float* __restrict__ wraw,
    const float* __restrict__ mw,
    unsigned* __restrict__ ws) {
  const int id = blockIdx.x * 256 + threadIdx.x;  // 1024 threads: (c,b)
  if (id >= 1024) return;
  const int c = id >> 7, b = id & 127;
  const float* pb = probes + b * HDIM + c * 8;
  const float* wb = wraw + b * NFREQ + c * 8;
  const float* mb = mw + b * NFREQ + c * 8;
  float pr[8], pi[8], w[8], m[8];
  *reinterpret_cast<float4*>(&pr[0]) = *reinterpret_cast<const float4*>(pb);
  *reinterpret_cast<float4*>(&pr[4]) = *reinterpret_cast<const float4*>(pb + 4);
  *reinterpret_cast<float4*>(&pi[0]) = *reinterpret_cast<const float4*>(pb + NFREQ);
  *reinterpret_cast<float4*>(&pi[4]) = *reinterpret_cast<const float4*>(pb + NFREQ + 4);
  *reinterpret_cast<float4*>(&w[0])  = *reinterpret_cast<const float4*>(wb);
  *reinterpret_cast<float4*>(&w[4])  = *reinterpret_cast<const float4*>(wb + 4);
  *reinterpret_cast<float4*>(&m[0])  = *reinterpret_cast<const float4*>(mb);
  *reinterpret_cast<float4*>(&m[4])  = *reinterpret_cast<const float4*>(mb + 4);
  unsigned ep[8], wp[4], mp[4];
  #pragma unroll
  for (int j = 0; j < 8; ++j) {
    h2 v = {(_Float16)pr[j], (_Float16)pi[j]};
    ep[j] = U32(v);
  }
  #pragma unroll
  for (int k = 0; k < 4; ++k) {
    float w0 = w[2 * k], w1 = w[2 * k + 1];
    float n0 = -(fmaxf(w0, 0.0f) + log1pf(expf(-fabsf(w0))));  // -softplus
    float n1 = -(fmaxf(w1, 0.0f) + log1pf(expf(-fabsf(w1))));
    h2 vw = {(_Float16)n0, (_Float16)n1};
    h2 vm = {(_Float16)m[2 * k], (_Float16)m[2 * k + 1]};
    wp[k] = U32(vw);
    mp[k] = U32(vm);
  }
  unsigned* EP = ws + (size_t)(c * 128 + b) * 8;
  *reinterpret_cast<uint4*>(EP)     = make_uint4(ep[0], ep[1], ep[2], ep[3]);
  *reinterpret_cast<uint4*>(EP + 4) = make_uint4(ep[4], ep[5], ep[6], ep[7]);
  unsigned* WP = ws + 8192 + (size_t)(c * 128 + b) * 4;
  *reinterpret_cast<uint4*>(WP) = make_uint4(wp[0], wp[1], wp[2], wp[3]);
  unsigned* MP = ws + 12288 + (size_t)(c * 128 + b) * 4;
  *reinterpret_cast<uint4*>(MP) = make_uint4(mp[0], mp[1], mp[2], mp[3]);
}

// ---------- scorer11: r9 math, occupancy-first shape ----------
// Block = 128 thr = 2 waves (fh0, fh1) over the SAME 4 queries.
// Wave = 4q x 128 bins (lane=bin, 2 copies) x 32 freqs (fh half).
// 4096 blocks -> 16 blocks/CU; __launch_bounds__(128,8) pins VGPR<=64 ->
// 8 waves/SIMD resident (vs 4 in r5-r10) to hide VMEM/LDS/trans latency.
__global__ __launch_bounds__(128, 8) void scorer11(
    const float* __restrict__ Q,
    const unsigned* __restrict__ ws,
    const float* __restrict__ bias,
    float* __restrict__ out) {
  __shared__ __align__(16) unsigned qep[4 * 64];  // [q][f] (nqr,nqi) h2 ; 1 KB
  __shared__ __align__(16) unsigned qqm[4 * 32];  // [q][fp] (qm0,qm1) h2 ; 0.5 KB
  __shared__ float part[4][2][64];                // fh1 partials ; 2 KB
  const int t = threadIdx.x;
  const int qblk = blockIdx.x * 4;

  // ---- Phase 1: normalize the block's 4 queries (32 lanes/query) ----
  {
    const int q = t >> 5;          // 0..3
    const int seg = t & 31;        // freq pair: f = seg*2, seg*2+1
    const float* qp = Q + (size_t)(qblk + q) * HDIM + seg * 2;
    const float2 r = *reinterpret_cast<const float2*>(qp);
    const float2 i = *reinterpret_cast<const float2*>(qp + NFREQ);
    float s = r.x * r.x + r.y * r.y + i.x * i.x + i.y * i.y;
    s += __shfl_xor(s, 1, 32);
    s += __shfl_xor(s, 2, 32);
    s += __shfl_xor(s, 4, 32);
    s += __shfl_xor(s, 8, 32);
    s += __shfl_xor(s, 16, 32);
    const float inv = 1.0f / (__builtin_amdgcn_sqrtf(s) + EPSF);
    const float qr0 = r.x * inv, qi0 = i.x * inv;
    const float qr1 = r.y * inv, qi1 = i.y * inv;
    h2 e0 = {(_Float16)(-qr0), (_Float16)(-qi0)};
    h2 e1 = {(_Float16)(-qr1), (_Float16)(-qi1)};
    *reinterpret_cast<uint2*>(&qep[q * 64 + seg * 2]) = make_uint2(U32(e0), U32(e1));
    const float qm0 = __builtin_amdgcn_sqrtf(fmaf(qr0, qr0, fmaf(qi0, qi0, EPSF)));
    const float qm1 = __builtin_amdgcn_sqrtf(fmaf(qr1, qr1, fmaf(qi1, qi1, EPSF)));
    h2 vm = {(_Float16)qm0, (_Float16)qm1};
    qqm[q * 32 + seg] = U32(vm);
  }
  __syncthreads();

  // ---- Phase 2: main loop (this wave's 32-freq half) ----
  const int lane = t & 63;
  const int fh = __builtin_amdgcn_readfirstlane(t >> 6);

  float acc[4][2];
  #pragma unroll
  for (int q = 0; q < 4; ++q) acc[q][0] = acc[q][1] = 0.0f;

  #pragma unroll 1
  for (int ci = 0; ci < 4; ++ci) {
    const int c = fh * 4 + ci;
    // per-lane probe words for this 8-freq chunk, both bin-copies
    const unsigned* EPb = ws + (size_t)(c * 128 + lane) * 8;
    const unsigned* WPb = ws + 8192 + (size_t)(c * 128 + lane) * 4;
    const unsigned* MPb = ws + 12288 + (size_t)(c * 128 + lane) * 4;
    const uint4 e0a = *reinterpret_cast<const uint4*>(EPb);
    const uint4 e0b = *reinterpret_cast<const uint4*>(EPb + 4);
    const uint4 e1a = *reinterpret_cast<const uint4*>(EPb + 512);
    const uint4 e1b = *reinterpret_cast<const uint4*>(EPb + 516);
    const uint4 w0v = *reinterpret_cast<const uint4*>(WPb);
    const uint4 w1v = *reinterpret_cast<const uint4*>(WPb + 256);
    const uint4 m0v = *reinterpret_cast<const uint4*>(MPb);
    const uint4 m1v = *reinterpret_cast<const uint4*>(MPb + 256);
    const unsigned ep[2][8] = {
        {e0a.x, e0a.y, e0a.z, e0a.w, e0b.x, e0b.y, e0b.z, e0b.w},
        {e1a.x, e1a.y, e1a.z, e1a.w, e1b.x, e1b.y, e1b.z, e1b.w}};
    const unsigned wp[2][4] = {{w0v.x, w0v.y, w0v.z, w0v.w},
                               {w1v.x, w1v.y, w1v.z, w1v.w}};
    const unsigned mp[2][4] = {{m0v.x, m0v.y, m0v.z, m0v.w},
                               {m1v.x, m1v.y, m1v.z, m1v.w}};
    #pragma unroll
    for (int q = 0; q < 4; ++q) {
      const uint4 qa = *reinterpret_cast<const uint4*>(&qep[q * 64 + c * 8]);
      const uint4 qb = *reinterpret_cast<const uint4*>(&qep[q * 64 + c * 8 + 4]);
      const uint4 qm4 = *reinterpret_cast<const uint4*>(&qqm[q * 32 + c * 4]);
      const unsigned qe[8] = {qa.x, qa.y, qa.z, qa.w, qb.x, qb.y, qb.z, qb.w};
      const unsigned qmw[4] = {qm4.x, qm4.y, qm4.z, qm4.w};
      #pragma unroll
      for (int bc = 0; bc < 2; ++bc) {
        float da = acc[q][bc];
        #pragma unroll
        for (int fp = 0; fp < 4; ++fp) {
          h2 e0 = B2(ep[bc][2 * fp])     + B2(qe[2 * fp]);   // v_pk_add_f16
          h2 e1 = B2(ep[bc][2 * fp + 1]) + B2(qe[2 * fp + 1]);
          float d0 = __builtin_amdgcn_fdot2(e0, e0, EPSF, false);
          float d1 = __builtin_amdgcn_fdot2(e1, e1, EPSF, false);
          h2 dp = cvt_pk(__builtin_amdgcn_sqrtf(d0), __builtin_amdgcn_sqrtf(d1));
          da = __builtin_amdgcn_fdot2(dp, B2(wp[bc][fp]), da, false);       // distance
          da = __builtin_amdgcn_fdot2(B2(qmw[fp]), B2(mp[bc][fp]), da, false); // magnitude
        }
        acc[q][bc] = da;
      }
    }
  }

  // ---- Phase 3: fh-combine + store ----
  if (fh == 1) {
    #pragma unroll
    for (int q = 0; q < 4; ++q) {
      part[q][0][lane] = acc[q][0];
      part[q][1][lane] = acc[q][1];
    }
  }
  __syncthreads();
  if (fh == 0) {
    const float bias0 = bias[lane];
    const float bias1 = bias[64 + lane];
    #pragma unroll
    for (int q = 0; q < 4; ++q) {
      const size_t row = (size_t)(qblk + q) * NBINS;
      out[row + lane]      = acc[q][0] + part[q][0][lane] + bias0;
      out[row + 64 + lane] = acc[q][1] + part[q][1][lane] + bias1;
    }
  }
}

extern "C" void kernel_launch(void* const* d_in, const int* in_sizes, int n_in,
                              void* d_out, int out_size, void* d_ws, size_t ws_size,
                              hipStream_t stream) {
  const float* Q      = (const float*)d_in[0];
  const float* probes = (const float*)d_in[1];
  const float* wraw   = (const float*)d_in[2];
  const float* mw     = (const float*)d_in[3];
  const float* bias   = (const float*)d_in[4];
  float* out = (float*)d_out;
  unsigned* ws = (unsigned*)d_ws;  // 64 KiB needed

  pack8<<<4, 256, 0, stream>>>(probes, wraw, mw, ws);
  scorer11<<<NQ / 4, 128, 0, stream>>>(Q, ws, bias, out);
}

// Round 12
// 37.292 us; speedup vs baseline: 1.2169x; 1.0008x over previous
//
#include <hip/hip_runtime.h>

#define NBINS 128
#define NFREQ 64
#define HDIM 128
#define NQ 16384
#define EPSF 1e-8f

typedef _Float16 h2 __attribute__((ext_vector_type(2)));
#define B2(x) __builtin_bit_cast(h2, (x))
#define U32(x) __builtin_bit_cast(unsigned, (x))

__device__ __forceinline__ h2 cvt_pk(float a, float b) {
  return __builtin_bit_cast(h2, __builtin_amdgcn_cvt_pkrtz(a, b));
}

// d_ws layout (f16 probe pack, 64 KiB; identical to rounds 9/11):
//   EP[c][b][fj] : (pr,pi) h2 word; c=0..7 (8-freq chunk), b=0..127, fj=0..7
//                  word idx (c*128+b)*8+fj                       -> 32 KiB
//   WP[c][b][fp] : (-softplus(w)) h2 pairs                       -> @ +8192 words
//   MP[c][b][fp] : (mw) h2 pairs                                 -> @ +12288 words
#define WS_NEEDED (64 * 1024)

// ---------- probe-pack kernel (unchanged) ----------
__global__ __launch_bounds__(256) void pack8(
    const float* __restrict__ probes,
    const float* __restrict__ wraw,
    const float* __restrict__ mw,
    unsigned* __restrict__ ws) {
  const int id = blockIdx.x * 256 + threadIdx.x;  // 1024 threads: (c,b)
  if (id >= 1024) return;
  const int c = id >> 7, b = id & 127;
  const float* pb = probes + b * HDIM + c * 8;
  const float* wb = wraw + b * NFREQ + c * 8;
  const float* mb = mw + b * NFREQ + c * 8;
  float pr[8], pi[8], w[8], m[8];
  *reinterpret_cast<float4*>(&pr[0]) = *reinterpret_cast<const float4*>(pb);
  *reinterpret_cast<float4*>(&pr[4]) = *reinterpret_cast<const float4*>(pb + 4);
  *reinterpret_cast<float4*>(&pi[0]) = *reinterpret_cast<const float4*>(pb + NFREQ);
  *reinterpret_cast<float4*>(&pi[4]) = *reinterpret_cast<const float4*>(pb + NFREQ + 4);
  *reinterpret_cast<float4*>(&w[0])  = *reinterpret_cast<const float4*>(wb);
  *reinterpret_cast<float4*>(&w[4])  = *reinterpret_cast<const float4*>(wb + 4);
  *reinterpret_cast<float4*>(&m[0])  = *reinterpret_cast<const float4*>(mb);
  *reinterpret_cast<float4*>(&m[4])  = *reinterpret_cast<const float4*>(mb + 4);
  unsigned ep[8], wp[4], mp[4];
  #pragma unroll
  for (int j = 0; j < 8; ++j) {
    h2 v = {(_Float16)pr[j], (_Float16)pi[j]};
    ep[j] = U32(v);
  }
  #pragma unroll
  for (int k = 0; k < 4; ++k) {
    float w0 = w[2 * k], w1 = w[2 * k + 1];
    float n0 = -(fmaxf(w0, 0.0f) + log1pf(expf(-fabsf(w0))));  // -softplus
    float n1 = -(fmaxf(w1, 0.0f) + log1pf(expf(-fabsf(w1))));
    h2 vw = {(_Float16)n0, (_Float16)n1};
    h2 vm = {(_Float16)m[2 * k], (_Float16)m[2 * k + 1]};
    wp[k] = U32(vw);
    mp[k] = U32(vm);
  }
  unsigned* EP = ws + (size_t)(c * 128 + b) * 8;
  *reinterpret_cast<uint4*>(EP)     = make_uint4(ep[0], ep[1], ep[2], ep[3]);
  *reinterpret_cast<uint4*>(EP + 4) = make_uint4(ep[4], ep[5], ep[6], ep[7]);
  unsigned* WP = ws + 8192 + (size_t)(c * 128 + b) * 4;
  *reinterpret_cast<uint4*>(WP) = make_uint4(wp[0], wp[1], wp[2], wp[3]);
  unsigned* MP = ws + 12288 + (size_t)(c * 128 + b) * 4;
  *reinterpret_cast<uint4*>(MP) = make_uint4(mp[0], mp[1], mp[2], mp[3]);
}

// ---------- scorer12: r11 math, register-dieted to fit 64 VGPR / 8 waves ----------
// Only change vs r11: per-(q,c) LDS q-loads split into per-(q,c,half) b128+b64
// (transient q regs 12 -> 6), keeping natural VGPR demand ~58 so the
// __launch_bounds__(128,8) cap is satisfiable WITHOUT spill/remat.
__global__ __launch_bounds__(128, 8) void scorer12(
    const float* __restrict__ Q,
    const unsigned* __restrict__ ws,
    const float* __restrict__ bias,
    float* __restrict__ out) {
  __shared__ __align__(16) unsigned qep[4 * 64];  // [q][f] (nqr,nqi) h2 ; 1 KB
  __shared__ __align__(16) unsigned qqm[4 * 32];  // [q][fp] (qm0,qm1) h2 ; 0.5 KB
  __shared__ float part[4][2][64];                // fh1 partials ; 2 KB
  const int t = threadIdx.x;
  const int qblk = blockIdx.x * 4;

  // ---- Phase 1: normalize the block's 4 queries (32 lanes/query) ----
  {
    const int q = t >> 5;          // 0..3
    const int seg = t & 31;        // freq pair: f = seg*2, seg*2+1
    const float* qp = Q + (size_t)(qblk + q) * HDIM + seg * 2;
    const float2 r = *reinterpret_cast<const float2*>(qp);
    const float2 i = *reinterpret_cast<const float2*>(qp + NFREQ);
    float s = r.x * r.x + r.y * r.y + i.x * i.x + i.y * i.y;
    s += __shfl_xor(s, 1, 32);
    s += __shfl_xor(s, 2, 32);
    s += __shfl_xor(s, 4, 32);
    s += __shfl_xor(s, 8, 32);
    s += __shfl_xor(s, 16, 32);
    const float inv = 1.0f / (__builtin_amdgcn_sqrtf(s) + EPSF);
    const float qr0 = r.x * inv, qi0 = i.x * inv;
    const float qr1 = r.y * inv, qi1 = i.y * inv;
    h2 e0 = {(_Float16)(-qr0), (_Float16)(-qi0)};
    h2 e1 = {(_Float16)(-qr1), (_Float16)(-qi1)};
    *reinterpret_cast<uint2*>(&qep[q * 64 + seg * 2]) = make_uint2(U32(e0), U32(e1));
    const float qm0 = __builtin_amdgcn_sqrtf(fmaf(qr0, qr0, fmaf(qi0, qi0, EPSF)));
    const float qm1 = __builtin_amdgcn_sqrtf(fmaf(qr1, qr1, fmaf(qi1, qi1, EPSF)));
    h2 vm = {(_Float16)qm0, (_Float16)qm1};
    qqm[q * 32 + seg] = U32(vm);
  }
  __syncthreads();

  // ---- Phase 2: main loop (this wave's 32-freq half) ----
  const int lane = t & 63;
  const int fh = __builtin_amdgcn_readfirstlane(t >> 6);

  float acc[4][2];
  #pragma unroll
  for (int q = 0; q < 4; ++q) acc[q][0] = acc[q][1] = 0.0f;

  #pragma unroll 1
  for (int ci = 0; ci < 4; ++ci) {
    const int c = fh * 4 + ci;
    // per-lane probe words for this 8-freq chunk, both bin-copies (32 u32)
    const unsigned* EPb = ws + (size_t)(c * 128 + lane) * 8;
    const unsigned* WPb = ws + 8192 + (size_t)(c * 128 + lane) * 4;
    const unsigned* MPb = ws + 12288 + (size_t)(c * 128 + lane) * 4;
    const uint4 e0a = *reinterpret_cast<const uint4*>(EPb);
    const uint4 e0b = *reinterpret_cast<const uint4*>(EPb + 4);
    const uint4 e1a = *reinterpret_cast<const uint4*>(EPb + 512);
    const uint4 e1b = *reinterpret_cast<const uint4*>(EPb + 516);
    const uint4 w0v = *reinterpret_cast<const uint4*>(WPb);
    const uint4 w1v = *reinterpret_cast<const uint4*>(WPb + 256);
    const uint4 m0v = *reinterpret_cast<const uint4*>(MPb);
    const uint4 m1v = *reinterpret_cast<const uint4*>(MPb + 256);
    const unsigned ep[2][8] = {
        {e0a.x, e0a.y, e0a.z, e0a.w, e0b.x, e0b.y, e0b.z, e0b.w},
        {e1a.x, e1a.y, e1a.z, e1a.w, e1b.x, e1b.y, e1b.z, e1b.w}};
    const unsigned wp[2][4] = {{w0v.x, w0v.y, w0v.z, w0v.w},
                               {w1v.x, w1v.y, w1v.z, w1v.w}};
    const unsigned mp[2][4] = {{m0v.x, m0v.y, m0v.z, m0v.w},
                               {m1v.x, m1v.y, m1v.z, m1v.w}};
    #pragma unroll
    for (int q = 0; q < 4; ++q) {
      #pragma unroll
      for (int half = 0; half < 2; ++half) {
        // slim q-transients: 4+2 words instead of 12
        const uint4 qa = *reinterpret_cast<const uint4*>(&qep[q * 64 + c * 8 + half * 4]);
        const uint2 qm2 = *reinterpret_cast<const uint2*>(&qqm[q * 32 + c * 4 + half * 2]);
        const unsigned qe[4] = {qa.x, qa.y, qa.z, qa.w};
        const unsigned qmw[2] = {qm2.x, qm2.y};
        #pragma unroll
        for (int bc = 0; bc < 2; ++bc) {
          float da = acc[q][bc];
          #pragma unroll
          for (int fp = 0; fp < 2; ++fp) {
            const int wi = half * 4 + 2 * fp;
            h2 e0 = B2(ep[bc][wi])     + B2(qe[2 * fp]);      // v_pk_add_f16
            h2 e1 = B2(ep[bc][wi + 1]) + B2(qe[2 * fp + 1]);
            float d0 = __builtin_amdgcn_fdot2(e0, e0, EPSF, false);
            float d1 = __builtin_amdgcn_fdot2(e1, e1, EPSF, false);
            h2 dp = cvt_pk(__builtin_amdgcn_sqrtf(d0), __builtin_amdgcn_sqrtf(d1));
            da = __builtin_amdgcn_fdot2(dp, B2(wp[bc][half * 2 + fp]), da, false);
            da = __builtin_amdgcn_fdot2(B2(qmw[fp]), B2(mp[bc][half * 2 + fp]), da, false);
          }
          acc[q][bc] = da;
        }
      }
    }
  }

  // ---- Phase 3: fh-combine + store ----
  if (fh == 1) {
    #pragma unroll
    for (int q = 0; q < 4; ++q) {
      part[q][0][lane] = acc[q][0];
      part[q][1][lane] = acc[q][1];
    }
  }
  __syncthreads();
  if (fh == 0) {
    const float bias0 = bias[lane];
    const float bias1 = bias[64 + lane];
    #pragma unroll
    for (int q = 0; q < 4; ++q) {
      const size_t row = (size_t)(qblk + q) * NBINS;
      out[row + lane]      = acc[q][0] + part[q][0][lane] + bias0;
      out[row + 64 + lane] = acc[q][1] + part[q][1][lane] + bias1;
    }
  }
}

extern "C" void kernel_launch(void* const* d_in, const int* in_sizes, int n_in,
                              void* d_out, int out_size, void* d_ws, size_t ws_size,
                              hipStream_t stream) {
  const float* Q      = (const float*)d_in[0];
  const float* probes = (const float*)d_in[1];
  const float* wraw   = (const float*)d_in[2];
  const float* mw     = (const float*)d_in[3];
  const float* bias   = (const float*)d_in[4];
  float* out = (float*)d_out;
  unsigned* ws = (unsigned*)d_ws;  // 64 KiB needed

  pack8<<<4, 256, 0, stream>>>(probes, wraw, mw, ws);
  scorer12<<<NQ / 4, 128, 0, stream>>>(Q, ws, bias, out);
}